// Round 1
// baseline (169.296 us; speedup 1.0000x reference)
//
#include <hip/hip_runtime.h>
#include <math.h>

#define N_SAMPLES 2048
#define E_EDGES   4096
#define NSPLIT    32
#define ROWS_PER  (N_SAMPLES / NSPLIT)   // 64

// op encoding: {type(0=u3,1=cx), a(theta offset / control), b(wire / target)}
__device__ __constant__ int d_ops[34][3] = {
    {0,0,0},{0,3,1},{1,0,1},
    {0,6,2},{0,9,3},{1,3,2},
    {0,12,4},{0,15,5},{1,4,5},
    {0,18,6},{0,21,7},{1,7,6},
    {0,24,8},{0,27,9},{1,8,9},
    {0,30,10},{0,33,11},{1,11,10},
    {0,36,1},{0,39,2},{1,1,2},
    {0,42,5},{0,45,6},{1,6,5},
    {0,48,9},{0,51,10},{1,10,9},
    {0,54,2},{0,57,5},{1,2,5},
    {0,60,5},{0,63,9},{1,5,9},
    {0,66,4},
};

// ---------------- Kernel A: split-K partials of bo = Ro^T X, bi = Ri^T X ----
__global__ __launch_bounds__(256) void k_partial(const float* __restrict__ Ri,
                                                 const float* __restrict__ Ro,
                                                 const float* __restrict__ X,
                                                 float* __restrict__ pbo,
                                                 float* __restrict__ pbi) {
    const int ec = blockIdx.x;   // 0..3  (1024-column chunk)
    const int ns = blockIdx.y;   // 0..31 (64-row chunk)
    const int t  = threadIdx.x;
    const float4* Ri4 = reinterpret_cast<const float4*>(Ri);
    const float4* Ro4 = reinterpret_cast<const float4*>(Ro);
    const float4* X4  = reinterpret_cast<const float4*>(X);

    float abo[4][4], abi[4][4];
#pragma unroll
    for (int c = 0; c < 4; ++c)
#pragma unroll
        for (int d = 0; d < 4; ++d) { abo[c][d] = 0.f; abi[c][d] = 0.f; }

    const int v = ec * 256 + t;  // float4 column index (0..1023)
    const int n0 = ns * ROWS_PER;
    for (int n = n0; n < n0 + ROWS_PER; ++n) {
        float4 xv = X4[n];
        float4 ro = Ro4[(size_t)n * 1024 + v];
        float4 ri = Ri4[(size_t)n * 1024 + v];
        float xs[4]  = {xv.x, xv.y, xv.z, xv.w};
        float ros[4] = {ro.x, ro.y, ro.z, ro.w};
        float ris[4] = {ri.x, ri.y, ri.z, ri.w};
#pragma unroll
        for (int c = 0; c < 4; ++c)
#pragma unroll
            for (int d = 0; d < 4; ++d) {
                abo[c][d] += ros[c] * xs[d];
                abi[c][d] += ris[c] * xs[d];
            }
    }

    float4* pbo4 = reinterpret_cast<float4*>(pbo);
    float4* pbi4 = reinterpret_cast<float4*>(pbi);
#pragma unroll
    for (int c = 0; c < 4; ++c) {
        size_t idx = (size_t)ns * E_EDGES + 4 * (size_t)v + c;  // per-e float4
        pbo4[idx] = make_float4(abo[c][0], abo[c][1], abo[c][2], abo[c][3]);
        pbi4[idx] = make_float4(abi[c][0], abi[c][1], abi[c][2], abi[c][3]);
    }
}

// ---------------- Kernel B: reduce partials -> bo, bi (float4 per e) --------
__global__ __launch_bounds__(256) void k_reduce(const float* __restrict__ pbo,
                                                const float* __restrict__ pbi,
                                                float* __restrict__ bo,
                                                float* __restrict__ bi) {
    const int e = blockIdx.x * 256 + threadIdx.x;   // 0..4095
    const float4* pbo4 = reinterpret_cast<const float4*>(pbo);
    const float4* pbi4 = reinterpret_cast<const float4*>(pbi);
    double so[4] = {0, 0, 0, 0}, si[4] = {0, 0, 0, 0};
    for (int ns = 0; ns < NSPLIT; ++ns) {
        float4 a = pbo4[(size_t)ns * E_EDGES + e];
        float4 b = pbi4[(size_t)ns * E_EDGES + e];
        so[0] += a.x; so[1] += a.y; so[2] += a.z; so[3] += a.w;
        si[0] += b.x; si[1] += b.y; si[2] += b.z; si[3] += b.w;
    }
    reinterpret_cast<float4*>(bo)[e] =
        make_float4((float)so[0], (float)so[1], (float)so[2], (float)so[3]);
    reinterpret_cast<float4*>(bi)[e] =
        make_float4((float)si[0], (float)si[1], (float)si[2], (float)si[3]);
}

// ---------------- Kernel C: fused M-row + 12-qubit statevector sim ----------
__global__ __launch_bounds__(256) void k_sim(const float* __restrict__ Ri,
                                             const float* __restrict__ Ro,
                                             const float* __restrict__ ev,
                                             const float* __restrict__ X,
                                             const float* __restrict__ theta,
                                             const float* __restrict__ bo,
                                             const float* __restrict__ bi,
                                             float* __restrict__ out) {
    __shared__ float  sre[4096];
    __shared__ float  sim_[4096];
    __shared__ double sred[4][8];
    __shared__ float  sTh[72];
    __shared__ double sMd[12];
    __shared__ float  sC[12], sS[12];

    const int n = blockIdx.x;
    const int t = threadIdx.x;

    if (t < 69) sTh[t] = theta[t];

    // ---- mi[n][:], mo[n][:] via double accumulation over e ----
    double acc[8];
#pragma unroll
    for (int j = 0; j < 8; ++j) acc[j] = 0.0;

    const float4* Ri4 = reinterpret_cast<const float4*>(Ri + (size_t)n * E_EDGES);
    const float4* Ro4 = reinterpret_cast<const float4*>(Ro + (size_t)n * E_EDGES);
    const float4* E4  = reinterpret_cast<const float4*>(ev);
    const float4* BO  = reinterpret_cast<const float4*>(bo);
    const float4* BI  = reinterpret_cast<const float4*>(bi);
#pragma unroll
    for (int k = 0; k < 4; ++k) {
        int v = t + 256 * k;
        float4 r_i = Ri4[v], r_o = Ro4[v], e4 = E4[v];
        float ri[4] = {r_i.x, r_i.y, r_i.z, r_i.w};
        float ro[4] = {r_o.x, r_o.y, r_o.z, r_o.w};
        float ee[4] = {e4.x, e4.y, e4.z, e4.w};
#pragma unroll
        for (int c = 0; c < 4; ++c) {
            float4 b_o = BO[4 * v + c], b_i = BI[4 * v + c];
            double rie = (double)(ri[c]) * (double)(ee[c]);
            double roe = (double)(ro[c]) * (double)(ee[c]);
            acc[0] += rie * b_o.x; acc[1] += rie * b_o.y;
            acc[2] += rie * b_o.z; acc[3] += rie * b_o.w;
            acc[4] += roe * b_i.x; acc[5] += roe * b_i.y;
            acc[6] += roe * b_i.z; acc[7] += roe * b_i.w;
        }
    }
#pragma unroll
    for (int off = 32; off >= 1; off >>= 1)
#pragma unroll
        for (int j = 0; j < 8; ++j) acc[j] += __shfl_down(acc[j], off);

    const int wid = t >> 6, lane = t & 63;
    if (lane == 0)
#pragma unroll
        for (int j = 0; j < 8; ++j) sred[wid][j] = acc[j];
    __syncthreads();
    if (t == 0) {
#pragma unroll
        for (int j = 0; j < 8; ++j)
            sMd[j] = sred[0][j] + sred[1][j] + sred[2][j] + sred[3][j];
#pragma unroll
        for (int d = 0; d < 4; ++d) sMd[8 + d] = (double)X[n * 4 + d];
    }
    __syncthreads();
    if (t < 12) {
        double a = 0.5 * sMd[t];
        double s, c;
        sincos(a, &s, &c);   // double-precision: M can be O(1000) rad
        sC[t] = (float)c; sS[t] = (float)s;
    }
    __syncthreads();

    // ---- product state |psi> = prod_q RY(M_q)|0>; idx = t + 256*k ----
    // bits 0..7 of idx = t (wires 4..11), bits 8..11 = k (wires 0..3)
    float pref = 1.f;
#pragma unroll
    for (int w = 4; w < 12; ++w) {
        int bit = (t >> (11 - w)) & 1;
        pref *= bit ? sS[w] : sC[w];
    }
#pragma unroll
    for (int k = 0; k < 16; ++k) {
        float suf = 1.f;
#pragma unroll
        for (int w = 0; w < 4; ++w) {
            int bit = (k >> (3 - w)) & 1;
            suf *= bit ? sS[w] : sC[w];
        }
        sre[t + 256 * k] = pref * suf;
        sim_[t + 256 * k] = 0.f;
    }
    __syncthreads();

    // ---- circuit: wire w lives at bit (11 - w) ----
    for (int g = 0; g < 34; ++g) {
        const int ty = d_ops[g][0], a = d_ops[g][1], b = d_ops[g][2];
        if (ty == 0) {
            float th = sTh[a], ph = sTh[a + 1], lm = sTh[a + 2];
            float st, ct;   sincosf(0.5f * th, &st, &ct);
            float sl, cl;   sincosf(lm, &sl, &cl);
            float sp, cp;   sincosf(ph, &sp, &cp);
            float spl, cpl; sincosf(ph + lm, &spl, &cpl);
            const float u00  = ct;
            const float u01r = -cl * st, u01i = -sl * st;
            const float u10r =  cp * st, u10i =  sp * st;
            const float u11r = cpl * ct, u11i = spl * ct;
            const int bb = 11 - b;
            const int mlow = (1 << bb) - 1;
#pragma unroll
            for (int k = 0; k < 8; ++k) {
                int p  = t + 256 * k;
                int i0 = ((p >> bb) << (bb + 1)) | (p & mlow);
                int i1 = i0 | (1 << bb);
                float a0r = sre[i0], a0i = sim_[i0];
                float a1r = sre[i1], a1i = sim_[i1];
                float n0r = u00 * a0r + u01r * a1r - u01i * a1i;
                float n0i = u00 * a0i + u01r * a1i + u01i * a1r;
                float n1r = u10r * a0r - u10i * a0i + u11r * a1r - u11i * a1i;
                float n1i = u10r * a0i + u10i * a0r + u11r * a1i + u11i * a1r;
                sre[i0] = n0r; sim_[i0] = n0i;
                sre[i1] = n1r; sim_[i1] = n1i;
            }
        } else {
            // CNOT(control=a, target=b): swap target-bit pair where control=1
            const int bc = 11 - a, bt2 = 11 - b;
            const int lo = (bc < bt2) ? bc : bt2;
            const int hi = (bc < bt2) ? bt2 : bc;
#pragma unroll
            for (int k = 0; k < 4; ++k) {
                int q  = t + 256 * k;                                // 0..1023
                int x1 = ((q >> lo) << (lo + 1)) | (q & ((1 << lo) - 1));
                int x2 = ((x1 >> hi) << (hi + 1)) | (x1 & ((1 << hi) - 1));
                int iA = x2 | (1 << bc);
                int iB = iA | (1 << bt2);
                float tr = sre[iA]; sre[iA] = sre[iB]; sre[iB] = tr;
                float ti = sim_[iA]; sim_[iA] = sim_[iB]; sim_[iB] = ti;
            }
        }
        __syncthreads();
    }

    // ---- <Z_9>: sign by bit 2 of idx; bit 2 of (t+256k) = bit 2 of t ----
    double z = 0.0;
    const float sgn = ((t >> 2) & 1) ? -1.f : 1.f;
#pragma unroll
    for (int k = 0; k < 16; ++k) {
        int idx = t + 256 * k;
        float re = sre[idx], im = sim_[idx];
        z += (double)(sgn * (re * re + im * im));
    }
#pragma unroll
    for (int off = 32; off >= 1; off >>= 1) z += __shfl_down(z, off);
    if (lane == 0) sred[wid][0] = z;
    __syncthreads();
    if (t == 0) {
        double zt = sred[0][0] + sred[1][0] + sred[2][0] + sred[3][0];
        out[n] = (float)(3.14159265358979323846 * (1.0 - zt));
    }
}

extern "C" void kernel_launch(void* const* d_in, const int* in_sizes, int n_in,
                              void* d_out, int out_size, void* d_ws, size_t ws_size,
                              hipStream_t stream) {
    (void)in_sizes; (void)n_in; (void)out_size; (void)ws_size;
    const float* X  = (const float*)d_in[0];
    const float* ev = (const float*)d_in[1];
    const float* Ri = (const float*)d_in[2];
    const float* Ro = (const float*)d_in[3];
    const float* th = (const float*)d_in[4];
    float* out = (float*)d_out;

    float* pbo = (float*)d_ws;                              // [NSPLIT][4096][4]
    float* pbi = pbo + (size_t)NSPLIT * E_EDGES * 4;        // [NSPLIT][4096][4]
    float* bo  = pbi + (size_t)NSPLIT * E_EDGES * 4;        // [4096][4]
    float* bi  = bo  + (size_t)E_EDGES * 4;                 // [4096][4]

    hipLaunchKernelGGL(k_partial, dim3(4, NSPLIT), dim3(256), 0, stream,
                       Ri, Ro, X, pbo, pbi);
    hipLaunchKernelGGL(k_reduce, dim3(E_EDGES / 256), dim3(256), 0, stream,
                       pbo, pbi, bo, bi);
    hipLaunchKernelGGL(k_sim, dim3(N_SAMPLES), dim3(256), 0, stream,
                       Ri, Ro, ev, X, th, bo, bi, out);
}